// Round 7
// baseline (153.301 us; speedup 1.0000x reference)
//
#include <hip/hip_runtime.h>
#include <hip/hip_bf16.h>
#include <cstdint>
#include <cstddef>

typedef __bf16 bf16;
typedef __bf16 bf16x2 __attribute__((ext_vector_type(2)));
typedef __bf16 bf16x4 __attribute__((ext_vector_type(4)));
typedef __bf16 bf16x8 __attribute__((ext_vector_type(8)));
typedef float f32x4 __attribute__((ext_vector_type(4)));
typedef float f32x16 __attribute__((ext_vector_type(16)));
typedef unsigned int u32x4 __attribute__((ext_vector_type(4)));

#define S_LEN 2048
#define DM 1024
#define NH 16
#define HD 64
#define NQKV (4096 * 1024)   // tokens * DM
#define NW (1024 * 1024)
// (1/sqrt(64)) * log2(e): fold softmax scale + exp2 conversion into Q
#define QK_SCALE 0.18033688011112042f

__device__ __forceinline__ void gload_lds16(const bf16* g, bf16* l) {
  __builtin_amdgcn_global_load_lds(
      (const __attribute__((address_space(1))) void*)g,
      (__attribute__((address_space(3))) void*)l, 16, 0, 0);
}

__device__ __forceinline__ unsigned packbf(float lo, float hi) {
  bf16x2 t;
  t[0] = (bf16)lo;
  t[1] = (bf16)hi;
  return __builtin_bit_cast(unsigned, t);
}

// v_permlane32_swap_b32: new_a[l>=32] = b_old[l-32]; new_b[l<32] = a_old[l+32]
__device__ __forceinline__ void pl32swap(unsigned& a, unsigned& b) {
#if __has_builtin(__builtin_amdgcn_permlane32_swap)
  auto r = __builtin_amdgcn_permlane32_swap((int)a, (int)b, false, false);
  a = (unsigned)r[0];
  b = (unsigned)r[1];
#else
  asm volatile("v_permlane32_swap_b32 %0, %1" : "+v"(a), "+v"(b));
#endif
}

// ---------------- fused fp32 -> bf16 convert for all 7 tensors ----------------
__global__ __launch_bounds__(256) void cvt_all(
    const float* __restrict__ q, const float* __restrict__ k, const float* __restrict__ v,
    const float* __restrict__ Wq, const float* __restrict__ Wk, const float* __restrict__ Wv,
    const float* __restrict__ Wo, bf16* __restrict__ out) {
  const size_t i = ((size_t)blockIdx.x * 256 + threadIdx.x) * 8;
  const float* src;
  size_t off;
  if (i < (size_t)NQKV) { src = q; off = i; }
  else if (i < 2ull * NQKV) { src = k; off = i - NQKV; }
  else if (i < 3ull * NQKV) { src = v; off = i - 2ull * NQKV; }
  else {
    const size_t j = i - 3ull * NQKV;
    if (j < (size_t)NW) { src = Wq; off = j; }
    else if (j < 2ull * NW) { src = Wk; off = j - NW; }
    else if (j < 3ull * NW) { src = Wv; off = j - 2ull * NW; }
    else { src = Wo; off = j - 3ull * NW; }
  }
  const float4 a = *(const float4*)(src + off);
  const float4 b = *(const float4*)(src + off + 4);
  bf16x8 o;
  o[0] = (bf16)a.x; o[1] = (bf16)a.y; o[2] = (bf16)a.z; o[3] = (bf16)a.w;
  o[4] = (bf16)b.x; o[5] = (bf16)b.y; o[6] = (bf16)b.z; o[7] = (bf16)b.w;
  *(bf16x8*)(out + i) = o;
}

// ---------------- GEMM: Y[m,n] = sum_k A[m,k] * W[n,k] + bias[n] ----------------
// MODE 2: out fp32, row-major [M,N]   (final projection)
// MODE 3: fused QKV; seg = n0>>10: seg0 Q head-major*QK_SCALE, seg1 K head-major,
//         seg2 V per-head transposed [B,H,hd,S] via LDS-transposed epilogue.
// Both grids have nwg % 8 == 0 -> simple bijective XCD swizzle.
template <int MODE>
__global__ __launch_bounds__(256, 2) void gemm_bt(
    const bf16* __restrict__ A, const bf16* __restrict__ W,
    const float* __restrict__ bias0, const float* __restrict__ bias1,
    const float* __restrict__ bias2, void* __restrict__ Out,
    int M, int N, int K, float scale) {
  __shared__ __align__(16) bf16 sm[2 * 128 * 64];
  bf16* Asl = sm;
  bf16* Bsl = sm + 128 * 64;
  const int tid = threadIdx.x;
  const int lane = tid & 63, w = tid >> 6;
  const int wr = w >> 1, wc = w & 1;
  const int r16 = lane & 15, grp = lane >> 4;

  // XCD swizzle: consecutive blocks within an XCD share A-panels
  int flat = blockIdx.y * gridDim.x + blockIdx.x;
  const int cpx = (gridDim.x * gridDim.y) >> 3;
  flat = (flat & 7) * cpx + (flat >> 3);
  const int m0 = (flat / gridDim.x) * 128;
  const int n0 = (flat % gridDim.x) * 128;

  const int seg = n0 >> 10;
  const bf16* Ab = (MODE == 3) ? A + (size_t)seg * NQKV : A;

  f32x4 acc[4][4] = {};

  const int nk = K >> 6;
  for (int t = 0; t < nk; ++t) {
    const int k0 = t << 6;
    __syncthreads();
#pragma unroll
    for (int j = 0; j < 4; ++j) {
      const int lin = j * 256 + tid;
      const int rr = lin >> 3;
      const int cc = (lin & 7) * 8;
      gload_lds16(&Ab[(size_t)(m0 + rr) * K + k0 + cc], &Asl[lin * 8]);
      gload_lds16(&W[(size_t)(n0 + rr) * K + k0 + cc], &Bsl[lin * 8]);
    }
    __syncthreads();
#pragma unroll
    for (int kk = 0; kk < 2; ++kk) {
      bf16x8 af[4], bfr[4];
#pragma unroll
      for (int m = 0; m < 4; ++m)
        af[m] = *(const bf16x8*)&Asl[(wr * 64 + m * 16 + r16) * 64 + kk * 32 + grp * 8];
#pragma unroll
      for (int n = 0; n < 4; ++n)
        bfr[n] = *(const bf16x8*)&Bsl[(wc * 64 + n * 16 + r16) * 64 + kk * 32 + grp * 8];
#pragma unroll
      for (int m = 0; m < 4; ++m)
#pragma unroll
        for (int n = 0; n < 4; ++n)
          acc[m][n] = __builtin_amdgcn_mfma_f32_16x16x32_bf16(af[m], bfr[n], acc[m][n], 0, 0, 0);
    }
  }

  const float* bp = (MODE == 3) ? (seg == 0 ? bias0 : (seg == 1 ? bias1 : bias2)) : bias0;
  const float sc = (MODE == 3) ? (seg == 0 ? scale : 1.0f) : scale;

  if (MODE == 3 && seg == 2) {
    // ---- V^T epilogue: transpose each wave's 64x64 quadrant via LDS ----
    __syncthreads();  // all Asl/Bsl readers done
    bf16* T = sm + w * (32 * 76);
    const int b = (m0 + wr * 64) >> 11;
    const int srow0 = (m0 + wr * 64) & 2047;
    bf16* base2 = (bf16*)Out + 2 * (size_t)NQKV;
#pragma unroll
    for (int p = 0; p < 2; ++p) {
#pragma unroll
      for (int nn = 0; nn < 2; ++nn) {
        const int n = 2 * p + nn;
#pragma unroll
        for (int mq = 0; mq < 4; ++mq)
#pragma unroll
          for (int r = 0; r < 4; ++r) {
            const int d_l = nn * 16 + r16;
            const int s_l = mq * 16 + grp * 4 + r;
            const int cs = (n0 + wc * 64 + n * 16 + r16) & 1023;
            T[d_l * 76 + s_l] = (bf16)(acc[mq][n][r] + bp[cs]);
          }
      }
      __syncthreads();
#pragma unroll
      for (int j = 0; j < 4; ++j) {
        const int d_l = j * 8 + (lane >> 3);
        const int scnk = lane & 7;
        const uint2 lo = *(const uint2*)&T[d_l * 76 + scnk * 8];
        const uint2 hi = *(const uint2*)&T[d_l * 76 + scnk * 8 + 4];
        const int cs = (n0 + wc * 64 + p * 32 + d_l) & 1023;
        const int hh = cs >> 6, dd = cs & 63;
        bf16* dst = base2 + ((size_t)(b * NH + hh) * HD + dd) * S_LEN + srow0 + scnk * 8;
        uint4 val; val.x = lo.x; val.y = lo.y; val.z = hi.x; val.w = hi.y;
        *(uint4*)dst = val;
      }
      __syncthreads();
    }
    return;
  }

#pragma unroll
  for (int m = 0; m < 4; ++m) {
#pragma unroll
    for (int n = 0; n < 4; ++n) {
#pragma unroll
      for (int r = 0; r < 4; ++r) {
        const int row = m0 + wr * 64 + m * 16 + grp * 4 + r;
        const int col = n0 + wc * 64 + n * 16 + r16;
        const int cs = col & 1023;
        const float v = (acc[m][n][r] + bp[cs]) * sc;
        if (MODE == 3) {  // seg 0/1: head-major
          const int b = row >> 11, s = row & 2047, h = cs >> 6, d = cs & 63;
          bf16* base = (bf16*)Out + (size_t)seg * NQKV;
          base[((size_t)(b * NH + h) * S_LEN + s) * HD + d] = (bf16)v;
        } else {
          ((float*)Out)[(size_t)row * N + col] = v;
        }
      }
    }
  }
}

// ---------------- causal flash attention: dual-chain balanced waves ------------
// Block = 2 waves; wave w owns TWO 32-row q-chunks: light cL = 2j+w and heavy
// 63-cL (causal pairing). ntL = j+1, ntH = 32-j -> EVERY wave computes exactly
// 33 chunk-tiles (perfect balance, no tail). Both chains share the staged K/V
// tile AND the kf/vf LDS fragments (A-operands depend on key/d only), so the
// second chain costs only MFMA+VALU -- two independent chains give ILP~2 to
// hide each other's latencies (the round-6 bottleneck).
// 3-buffer LDS ring, counted vmcnt(8), one barrier per tile (T3/T4).
// QK^T swapped mfma(K,Q), PV swapped mfma(Vt,P): softmax state lane-local.
__global__ __launch_bounds__(128, 1) void attn_fwd7(
    const bf16* __restrict__ Qh, const bf16* __restrict__ Kh,
    const bf16* __restrict__ Vt, bf16* __restrict__ AO) {
  __shared__ __align__(16) bf16 Kl[3][64 * 64];
  __shared__ __align__(16) bf16 Vl[3][64 * 64];

  const int tid = threadIdx.x;
  const int lane = tid & 63, w = tid >> 6;   // 2 waves
  const int q31 = lane & 31, h = lane >> 5;

  // 512 blocks: xcd = bid&7 (4 heads/XCD); j = pair index 0..15 ascending ->
  // j=0 (32 iterations) dispatched first (heavy-iteration-first).
  const int bid = blockIdx.x;
  const int xcd = bid & 7;
  const int within = bid >> 3;           // 0..63
  const int j = within >> 2;             // 0..15
  const int bh = xcd * 4 + (within & 3);

  const int cL = 2 * j + w;              // light chunk (32 rows)
  const int qL = cL << 5;
  const int qH = (63 - cL) << 5;         // heavy partner chunk
  const int ntL = j + 1;                 // light K-tiles
  const int nt = 32 - j;                 // heavy K-tiles = staged tiles
  const int qgL = qL + q31, qgH = qH + q31;

  const bf16* Qb = Qh + (size_t)bh * S_LEN * HD;
  const bf16* Kb = Kh + (size_t)bh * S_LEN * HD;
  const bf16* Vb = Vt + (size_t)bh * HD * S_LEN;

  // staging offsets: 8KB tile = 512 x 16B; 128 threads x 4 issues (K and V each)
  int stK[4], stV[4], stL[4];
#pragma unroll
  for (int i = 0; i < 4; ++i) {
    const int lin = i * 128 + tid;       // 0..511
    const int row = lin >> 3;            // 0..63
    const int colb = (lin & 7) * 16;
    const int scol = colb ^ ((row & 7) << 4);
    stK[i] = row * HD + (scol >> 1);
    stV[i] = row * S_LEN + (scol >> 1);
    stL[i] = lin * 8;
  }

#define STAGE(t, buf)                                                          \
  {                                                                            \
    const bf16* kb_ = Kb + (size_t)(t) * 64 * HD;                              \
    const bf16* vb_ = Vb + (t) * 64;                                           \
    bf16* kd_ = &Kl[buf][0];                                                   \
    bf16* vd_ = &Vl[buf][0];                                                   \
    _Pragma("unroll") for (int i = 0; i < 4; ++i) {                            \
      gload_lds16(kb_ + stK[i], kd_ + stL[i]);                                 \
      gload_lds16(vb_ + stV[i], vd_ + stL[i]);                                 \
    }                                                                          \
  }

  // Q B-frags for both chains: col = q = lane&31, k = ks*16 + 8h + i
  bf16x8 qfL[4], qfH[4];
#pragma unroll
  for (int ks = 0; ks < 4; ++ks) {
    qfL[ks] = *(const bf16x8*)&Qb[(size_t)qgL * HD + ks * 16 + 8 * h];
    qfH[ks] = *(const bf16x8*)&Qb[(size_t)qgH * HD + ks * 16 + 8 * h];
  }

  f32x16 accL0 = {}, accL1 = {}, accH0 = {}, accH1 = {};
  float mL = -1e30f, lL = 0.f, mH = -1e30f, lH = 0.f;
  const int swz = (q31 & 7) << 4;

  // prologue: tiles 0,1 into buffers 0,1
  STAGE(0, 0)
  STAGE(1, 1)

#define PACK_HALF(P, PW, o0, o1)                                               \
  {                                                                            \
    unsigned wv[8];                                                            \
    _Pragma("unroll") for (int mm = 0; mm < 8; ++mm)                           \
        wv[mm] = packbf(P[2 * mm], P[2 * mm + 1]);                             \
    pl32swap(wv[0], wv[2]);                                                    \
    pl32swap(wv[1], wv[3]);                                                    \
    pl32swap(wv[4], wv[6]);                                                    \
    pl32swap(wv[5], wv[7]);                                                    \
    PW[o0][0] = wv[0]; PW[o0][1] = wv[1]; PW[o0][2] = wv[2]; PW[o0][3] = wv[3];\
    PW[o1][0] = wv[4]; PW[o1][1] = wv[5]; PW[o1][2] = wv[6]; PW[o1][3] = wv[7];\
  }

#define SOFTMAX_PACK(P0, P1, A0, A1, M, L, PW, SKIP1)                          \
  {                                                                            \
    float t_[16];                                                              \
    _Pragma("unroll") for (int r = 0; r < 16; ++r)                             \
        t_[r] = fmaxf(P0[r], P1[r]);                                           \
    _Pragma("unroll") for (int s = 8; s >= 1; s >>= 1)                         \
      _Pragma("unroll") for (int r = 0; r < s; ++r)                            \
          t_[r] = fmaxf(t_[r], t_[r + s]);                                     \
    const float pmax_ = fmaxf(t_[0], __shfl_xor(t_[0], 32));                   \
    if (!__all(pmax_ - M <= 8.0f)) {                                           \
      const float mn_ = fmaxf(M, pmax_);                                       \
      const float al_ = exp2f(M - mn_);                                        \
      M = mn_;                                                                 \
      L *= al_;                                                                \
      _Pragma("unroll") for (int r = 0; r < 16; ++r) {                         \
        A0[r] *= al_;                                                          \
        A1[r] *= al_;                                                          \
      }                                                                        \
    }                                                                          \
    float sv_[16];                                                             \
    _Pragma("unroll") for (int r = 0; r < 16; ++r) {                           \
      P0[r] = exp2f(P0[r] - M);                                                \
      P1[r] = exp2f(P1[r] - M);                                                \
      sv_[r] = P0[r] + P1[r];                                                  \
    }                                                                          \
    _Pragma("unroll") for (int s = 8; s >= 1; s >>= 1)                         \
      _Pragma("unroll") for (int r = 0; r < s; ++r) sv_[r] += sv_[r + s];      \
    L += sv_[0] + __shfl_xor(sv_[0], 32);                                      \
    PACK_HALF(P0, PW, 0, 1)                                                    \
    if (!(SKIP1)) PACK_HALF(P1, PW, 2, 3)                                      \
  }

#define PV_STEP(PW, ks, A0, A1)                                                \
  {                                                                            \
    u32x4 pu = {PW[ks][0], PW[ks][1], PW[ks][2], PW[ks][3]};                   \
    const bf16x8 pf_ = __builtin_bit_cast(bf16x8, pu);                         \
    A0 = __builtin_amdgcn_mfma_f32_32x32x16_bf16(vf[(ks) * 2 + 0], pf_, A0,    \
                                                 0, 0, 0);                     \
    A1 = __builtin_amdgcn_mfma_f32_32x32x16_bf16(vf[(ks) * 2 + 1], pf_, A1,    \
                                                 0, 0, 0);                     \
  }

  int cur = 0;
  for (int kt = 0; kt < nt; ++kt) {
    // tile kt landed when <=8 newer (tile kt+1's) stage-instrs outstanding
    if (kt + 1 < nt) asm volatile("s_waitcnt vmcnt(8)" ::: "memory");
    else             asm volatile("s_waitcnt vmcnt(0)" ::: "memory");
    __builtin_amdgcn_s_barrier();

    // stage tile kt+2 (its buffer's readers retired before this barrier)
    if (kt + 2 < nt) {
      int nxt = cur + 2; if (nxt >= 3) nxt -= 3;
      STAGE(kt + 2, nxt)
    }

    const int k0 = kt << 6;
    const bf16* KlC = &Kl[cur][0];
    const bf16* VlC = &Vl[cur][0];

    const bool liveL = kt < ntL;
    const bool skipL = (kt == ntL - 1) && (w == 0);  // light diag, upper half dead
    const bool skipH = (kt == nt - 1) && (w == 1);   // heavy diag, upper half dead

    // shared K A-frags (keys -> same for both chains)
    bf16x8 kf[8];
#pragma unroll
    for (int ks = 0; ks < 4; ++ks) {
      const int c = (32 * ks + 16 * h) ^ swz;
      kf[ks]     = *(const bf16x8*)((const char*)KlC + q31 * 128 + c);
      kf[4 + ks] = *(const bf16x8*)((const char*)KlC + (32 + q31) * 128 + c);
    }

    // ---- QK^T both chains ----
    f32x16 pL0 = {}, pL1 = {}, pH0 = {}, pH1 = {};
    __builtin_amdgcn_s_setprio(1);
    if (liveL) {
#pragma unroll
      for (int ks = 0; ks < 4; ++ks)
        pL0 = __builtin_amdgcn_mfma_f32_32x32x16_bf16(kf[ks], qfL[ks], pL0, 0, 0, 0);
      if (!skipL) {
#pragma unroll
        for (int ks = 0; ks < 4; ++ks)
          pL1 = __builtin_amdgcn_mfma_f32_32x32x16_bf16(kf[4 + ks], qfL[ks], pL1, 0, 0, 0);
      }
    }
#pragma unroll
    for (int ks = 0; ks < 4; ++ks)
      pH0 = __builtin_amdgcn_mfma_f32_32x32x16_bf16(kf[ks], qfH[ks], pH0, 0, 0, 0);
    if (!skipH) {
#pragma unroll
      for (int ks = 0; ks < 4; ++ks)
        pH1 = __builtin_amdgcn_mfma_f32_32x32x16_bf16(kf[4 + ks], qfH[ks], pH1, 0, 0, 0);
    }
    __builtin_amdgcn_s_setprio(0);

    // shared V A-frags (d rows -> same for both chains); hide under softmax
    bf16x8 vf[8];
#pragma unroll
    for (int ks = 0; ks < 4; ++ks)
#pragma unroll
      for (int db = 0; db < 2; ++db) {
        const int c = (32 * ks + 16 * h) ^ swz;
        vf[ks * 2 + db] =
            *(const bf16x8*)((const char*)VlC + (db * 32 + q31) * 128 + c);
      }

    // ---- causal masks (diag tiles); key row = (r&3)+8*(r>>2)+4h ----
    if (liveL && kt == ntL - 1) {
      if (skipL) {
#pragma unroll
        for (int r = 0; r < 16; ++r) {
          const int key = k0 + (r & 3) + 8 * (r >> 2) + 4 * h;
          if (key > qgL) pL0[r] = -1e30f;
          pL1[r] = -1e30f;
        }
      } else {
#pragma unroll
        for (int r = 0; r < 16; ++r) {
          const int key = k0 + 32 + (r & 3) + 8 * (r >> 2) + 4 * h;
          if (key > qgL) pL1[r] = -1e30f;
        }
      }
    }
    if (kt == nt - 1) {
      if (skipH) {
#pragma unroll
        for (int r = 0; r < 16; ++r) {
          const int key = k0 + (r & 3) + 8 * (r >> 2) + 4 * h;
          if (key > qgH) pH0[r] = -1e30f;
          pH1[r] = -1e30f;
        }
      } else {
#pragma unroll
        for (int r = 0; r < 16; ++r) {
          const int key = k0 + 32 + (r & 3) + 8 * (r >> 2) + 4 * h;
          if (key > qgH) pH1[r] = -1e30f;
        }
      }
    }

    // ---- softmax + pack, then PV (chains independent -> ILP) ----
    unsigned pwL[4][4], pwH[4][4];
    if (liveL) SOFTMAX_PACK(pL0, pL1, accL0, accL1, mL, lL, pwL, skipL)
    SOFTMAX_PACK(pH0, pH1, accH0, accH1, mH, lH, pwH, skipH)

    __builtin_amdgcn_s_setprio(1);
    if (liveL) {
      PV_STEP(pwL, 0, accL0, accL1)
      PV_STEP(pwL, 1, accL0, accL1)
      if (!skipL) {
        PV_STEP(pwL, 2, accL0, accL1)
        PV_STEP(pwL, 3, accL0, accL1)
      }
    }
    PV_STEP(pwH, 0, accH0, accH1)
    PV_STEP(pwH, 1, accH0, accH1)
    if (!skipH) {
      PV_STEP(pwH, 2, accH0, accH1)
      PV_STEP(pwH, 3, accH0, accH1)
    }
    __builtin_amdgcn_s_setprio(0);

    ++cur; if (cur == 3) cur = 0;
  }

  // ---- store both chains: O row = d = (r&3)+8*(r>>2)+4h (+32 for acc1) ----
  const int b = bh >> 4, hh = bh & 15;
#define STORE_CHAIN(A0, A1, LVAL, QG)                                          \
  {                                                                            \
    const float ro_ = 1.0f / (LVAL);                                           \
    bf16* orow_ = AO + ((size_t)(b * S_LEN + (QG))) * DM + hh * HD;            \
    _Pragma("unroll") for (int mm = 0; mm < 4; ++mm) {                         \
      bf16x4 ov0, ov1;                                                         \
      _Pragma("unroll") for (int t2 = 0; t2 < 4; ++t2) {                       \
        ov0[t2] = (bf16)(A0[4 * mm + t2] * ro_);                               \
        ov1[t2] = (bf16)(A1[4 * mm + t2] * ro_);                               \
      }                                                                        \
      *(bf16x4*)&orow_[8 * mm + 4 * h] = ov0;                                  \
      *(bf16x4*)&orow_[32 + 8 * mm + 4 * h] = ov1;                             \
    }                                                                          \
  }
  STORE_CHAIN(accL0, accL1, lL, qgL)
  STORE_CHAIN(accH0, accH1, lH, qgH)
#undef STORE_CHAIN
#undef PV_STEP
#undef SOFTMAX_PACK
#undef PACK_HALF
#undef STAGE
}

// ---------------- launch ----------------
extern "C" void kernel_launch(void* const* d_in, const int* in_sizes, int n_in,
                              void* d_out, int out_size, void* d_ws, size_t ws_size,
                              hipStream_t stream) {
  const float* q  = (const float*)d_in[0];
  const float* k  = (const float*)d_in[1];
  const float* v  = (const float*)d_in[2];
  const float* Wq = (const float*)d_in[3];
  const float* bq = (const float*)d_in[4];
  const float* Wk = (const float*)d_in[5];
  const float* bk = (const float*)d_in[6];
  const float* Wv = (const float*)d_in[7];
  const float* bv = (const float*)d_in[8];
  const float* Wo = (const float*)d_in[9];
  const float* bo = (const float*)d_in[10];

  const int NTOK = 2 * S_LEN;          // 4096

  bf16* qb  = (bf16*)d_ws;             // q,k,v bf16: 3 * NQKV (consecutive)
  bf16* Wqb = qb + 3 * (size_t)NQKV;   // Wq,Wk,Wv,Wo bf16: 4 * NW (consecutive)
  bf16* Wob = Wqb + 3 * (size_t)NW;
  bf16* Qh  = Wqb + 4 * (size_t)NW;    // Qh,Kh,Vt bf16: 3 * NQKV (consecutive)
  bf16* Kh  = Qh + (size_t)NQKV;
  bf16* Vt  = Kh + (size_t)NQKV;
  bf16* AO  = Vt + (size_t)NQKV;

  const int cvt_blocks = (3 * NQKV + 4 * NW) / 8 / 256;
  cvt_all<<<cvt_blocks, 256, 0, stream>>>(q, k, v, Wq, Wk, Wv, Wo, qb);

  // fused QKV projection: M=4096, N=3072, K=1024
  gemm_bt<3><<<dim3(3 * DM / 128, NTOK / 128), 256, 0, stream>>>(
      qb, Wqb, bq, bk, bv, Qh, NTOK, 3 * DM, DM, QK_SCALE);

  // attention: 512 blocks x 128 threads, dual-chain balanced waves
  attn_fwd7<<<dim3(512), 128, 0, stream>>>(Qh, Kh, Vt, AO);

  // output projection -> fp32 d_out
  gemm_bt<2><<<dim3(DM / 128, NTOK / 128), 256, 0, stream>>>(
      AO, Wob, bo, bo, bo, d_out, NTOK, DM, DM, 1.0f);
}

// Round 8
// 121.284 us; speedup vs baseline: 1.2640x; 1.2640x over previous
//
#include <hip/hip_runtime.h>
#include <hip/hip_bf16.h>
#include <cstdint>
#include <cstddef>

typedef __bf16 bf16;
typedef __bf16 bf16x2 __attribute__((ext_vector_type(2)));
typedef __bf16 bf16x4 __attribute__((ext_vector_type(4)));
typedef __bf16 bf16x8 __attribute__((ext_vector_type(8)));
typedef float f32x4 __attribute__((ext_vector_type(4)));
typedef float f32x16 __attribute__((ext_vector_type(16)));
typedef unsigned int u32x4 __attribute__((ext_vector_type(4)));

#define S_LEN 2048
#define DM 1024
#define NH 16
#define HD 64
#define NQKV (4096 * 1024)   // tokens * DM
#define NW (1024 * 1024)
// (1/sqrt(64)) * log2(e): fold softmax scale + exp2 conversion into Q
#define QK_SCALE 0.18033688011112042f

__device__ __forceinline__ void gload_lds16(const bf16* g, bf16* l) {
  __builtin_amdgcn_global_load_lds(
      (const __attribute__((address_space(1))) void*)g,
      (__attribute__((address_space(3))) void*)l, 16, 0, 0);
}

__device__ __forceinline__ unsigned packbf(float lo, float hi) {
  bf16x2 t;
  t[0] = (bf16)lo;
  t[1] = (bf16)hi;
  return __builtin_bit_cast(unsigned, t);
}

// v_permlane32_swap_b32: new_a[l>=32] = b_old[l-32]; new_b[l<32] = a_old[l+32]
__device__ __forceinline__ void pl32swap(unsigned& a, unsigned& b) {
#if __has_builtin(__builtin_amdgcn_permlane32_swap)
  auto r = __builtin_amdgcn_permlane32_swap((int)a, (int)b, false, false);
  a = (unsigned)r[0];
  b = (unsigned)r[1];
#else
  asm volatile("v_permlane32_swap_b32 %0, %1" : "+v"(a), "+v"(b));
#endif
}

// ---------------- fused fp32 -> bf16 convert for all 7 tensors ----------------
__global__ __launch_bounds__(256) void cvt_all(
    const float* __restrict__ q, const float* __restrict__ k, const float* __restrict__ v,
    const float* __restrict__ Wq, const float* __restrict__ Wk, const float* __restrict__ Wv,
    const float* __restrict__ Wo, bf16* __restrict__ out) {
  const size_t i = ((size_t)blockIdx.x * 256 + threadIdx.x) * 8;
  const float* src;
  size_t off;
  if (i < (size_t)NQKV) { src = q; off = i; }
  else if (i < 2ull * NQKV) { src = k; off = i - NQKV; }
  else if (i < 3ull * NQKV) { src = v; off = i - 2ull * NQKV; }
  else {
    const size_t j = i - 3ull * NQKV;
    if (j < (size_t)NW) { src = Wq; off = j; }
    else if (j < 2ull * NW) { src = Wk; off = j - NW; }
    else if (j < 3ull * NW) { src = Wv; off = j - 2ull * NW; }
    else { src = Wo; off = j - 3ull * NW; }
  }
  const float4 a = *(const float4*)(src + off);
  const float4 b = *(const float4*)(src + off + 4);
  bf16x8 o;
  o[0] = (bf16)a.x; o[1] = (bf16)a.y; o[2] = (bf16)a.z; o[3] = (bf16)a.w;
  o[4] = (bf16)b.x; o[5] = (bf16)b.y; o[6] = (bf16)b.z; o[7] = (bf16)b.w;
  *(bf16x8*)(out + i) = o;
}

// ---------------- GEMM: Y[m,n] = sum_k A[m,k] * W[n,k] + bias[n] ----------------
// MODE 2: out fp32, row-major [M,N]   (final projection)
// MODE 3: fused QKV; seg = n0>>10: seg0 Q head-major*QK_SCALE, seg1 K head-major,
//         seg2 V per-head transposed [B,H,hd,S] via LDS-transposed epilogue.
template <int MODE>
__global__ __launch_bounds__(256, 2) void gemm_bt(
    const bf16* __restrict__ A, const bf16* __restrict__ W,
    const float* __restrict__ bias0, const float* __restrict__ bias1,
    const float* __restrict__ bias2, void* __restrict__ Out,
    int M, int N, int K, float scale) {
  __shared__ __align__(16) bf16 sm[2 * 128 * 64];
  bf16* Asl = sm;
  bf16* Bsl = sm + 128 * 64;
  const int tid = threadIdx.x;
  const int lane = tid & 63, w = tid >> 6;
  const int wr = w >> 1, wc = w & 1;
  const int r16 = lane & 15, grp = lane >> 4;

  // XCD swizzle: consecutive blocks within an XCD share A-panels
  int flat = blockIdx.y * gridDim.x + blockIdx.x;
  const int cpx = (gridDim.x * gridDim.y) >> 3;
  flat = (flat & 7) * cpx + (flat >> 3);
  const int m0 = (flat / gridDim.x) * 128;
  const int n0 = (flat % gridDim.x) * 128;

  const int seg = n0 >> 10;
  const bf16* Ab = (MODE == 3) ? A + (size_t)seg * NQKV : A;

  f32x4 acc[4][4] = {};

  const int nk = K >> 6;
  for (int t = 0; t < nk; ++t) {
    const int k0 = t << 6;
    __syncthreads();
#pragma unroll
    for (int j = 0; j < 4; ++j) {
      const int lin = j * 256 + tid;
      const int rr = lin >> 3;
      const int cc = (lin & 7) * 8;
      gload_lds16(&Ab[(size_t)(m0 + rr) * K + k0 + cc], &Asl[lin * 8]);
      gload_lds16(&W[(size_t)(n0 + rr) * K + k0 + cc], &Bsl[lin * 8]);
    }
    __syncthreads();
#pragma unroll
    for (int kk = 0; kk < 2; ++kk) {
      bf16x8 af[4], bfr[4];
#pragma unroll
      for (int m = 0; m < 4; ++m)
        af[m] = *(const bf16x8*)&Asl[(wr * 64 + m * 16 + r16) * 64 + kk * 32 + grp * 8];
#pragma unroll
      for (int n = 0; n < 4; ++n)
        bfr[n] = *(const bf16x8*)&Bsl[(wc * 64 + n * 16 + r16) * 64 + kk * 32 + grp * 8];
#pragma unroll
      for (int m = 0; m < 4; ++m)
#pragma unroll
        for (int n = 0; n < 4; ++n)
          acc[m][n] = __builtin_amdgcn_mfma_f32_16x16x32_bf16(af[m], bfr[n], acc[m][n], 0, 0, 0);
    }
  }

  const float* bp = (MODE == 3) ? (seg == 0 ? bias0 : (seg == 1 ? bias1 : bias2)) : bias0;
  const float sc = (MODE == 3) ? (seg == 0 ? scale : 1.0f) : scale;

  if (MODE == 3 && seg == 2) {
    // ---- V^T epilogue: transpose each wave's 64x64 quadrant via LDS ----
    __syncthreads();  // all Asl/Bsl readers done
    bf16* T = sm + w * (32 * 76);
    const int b = (m0 + wr * 64) >> 11;
    const int srow0 = (m0 + wr * 64) & 2047;
    bf16* base2 = (bf16*)Out + 2 * (size_t)NQKV;
#pragma unroll
    for (int p = 0; p < 2; ++p) {
#pragma unroll
      for (int nn = 0; nn < 2; ++nn) {
        const int n = 2 * p + nn;
#pragma unroll
        for (int mq = 0; mq < 4; ++mq)
#pragma unroll
          for (int r = 0; r < 4; ++r) {
            const int d_l = nn * 16 + r16;
            const int s_l = mq * 16 + grp * 4 + r;
            const int cs = (n0 + wc * 64 + n * 16 + r16) & 1023;
            T[d_l * 76 + s_l] = (bf16)(acc[mq][n][r] + bp[cs]);
          }
      }
      __syncthreads();
#pragma unroll
      for (int j = 0; j < 4; ++j) {
        const int d_l = j * 8 + (lane >> 3);
        const int scnk = lane & 7;
        const uint2 lo = *(const uint2*)&T[d_l * 76 + scnk * 8];
        const uint2 hi = *(const uint2*)&T[d_l * 76 + scnk * 8 + 4];
        const int cs = (n0 + wc * 64 + p * 32 + d_l) & 1023;
        const int hh = cs >> 6, dd = cs & 63;
        bf16* dst = base2 + ((size_t)(b * NH + hh) * HD + dd) * S_LEN + srow0 + scnk * 8;
        uint4 val; val.x = lo.x; val.y = lo.y; val.z = hi.x; val.w = hi.y;
        *(uint4*)dst = val;
      }
      __syncthreads();
    }
    return;
  }

#pragma unroll
  for (int m = 0; m < 4; ++m) {
#pragma unroll
    for (int n = 0; n < 4; ++n) {
#pragma unroll
      for (int r = 0; r < 4; ++r) {
        const int row = m0 + wr * 64 + m * 16 + grp * 4 + r;
        const int col = n0 + wc * 64 + n * 16 + r16;
        const int cs = col & 1023;
        const float v = (acc[m][n][r] + bp[cs]) * sc;
        if (MODE == 3) {  // seg 0/1: head-major
          const int b = row >> 11, s = row & 2047, h = cs >> 6, d = cs & 63;
          bf16* base = (bf16*)Out + (size_t)seg * NQKV;
          base[((size_t)(b * NH + h) * S_LEN + s) * HD + d] = (bf16)v;
        } else {
          ((float*)Out)[(size_t)row * N + col] = v;
        }
      }
    }
  }
}

// ---------------- causal flash attention: paired chunks, key-split waves --------
// 512 blocks x 4 waves. Block = (bh, chunk pair (c, 31-c) of 64 q-rows each),
// processed in two sequential phases -> EVERY block stages exactly 33 tiles
// (perfect balance; CU assignment irrelevant; kills the 50% drain tail seen as
// OccupancyPercent=12%). Within a phase, wave (qh=w>>1, kh=w&1) computes q-rows
// 32*qh..+31 x key-half 32*kh of each 64-key tile (half-width: 4 QK mfma +
// 16 exp2 + 4 PV mfma per wave-tile). Per q-half the two key-half waves keep
// independent online-softmax states, merged once per phase via LDS (split-K
// flash combine: O = (a0*O0 + a1*O1)/(a0*l0+a1*l1)).
// 3-buffer LDS ring, counted vmcnt(4) (T4), one barrier/tile. XOR-swizzled
// staging (rule #21). QK^T swapped mfma(K,Q), PV swapped mfma(Vt,P).
__global__ __launch_bounds__(256, 2) void attn_fwd8(
    const bf16* __restrict__ Qh, const bf16* __restrict__ Kh,
    const bf16* __restrict__ Vt, bf16* __restrict__ AO) {
  __shared__ __align__(16) bf16 Kl[3][64 * 64];
  __shared__ __align__(16) bf16 Vl[3][64 * 64];

  const int tid = threadIdx.x;
  const int lane = tid & 63, w = tid >> 6;
  const int q31 = lane & 31, h = lane >> 5;
  const int qh = w >> 1, kh = w & 1;
  const int koff = kh << 5;

  // 512 blocks: xcd = bid&7 (4 heads/XCD); p = chunk-pair index 0..15.
  const int bid = blockIdx.x;
  const int xcd = bid & 7;
  const int within = bid >> 3;           // 0..63
  const int bh = xcd * 4 + (within & 3);
  const int p = within >> 2;             // 0..15

  const bf16* Qb = Qh + (size_t)bh * S_LEN * HD;
  const bf16* Kb = Kh + (size_t)bh * S_LEN * HD;
  const bf16* Vb = Vt + (size_t)bh * HD * S_LEN;

  // staging offsets: 8KB tile = 512 x 16B; 256 threads x 2 issues (K and V)
  int stK[2], stV[2], stL[2];
#pragma unroll
  for (int i = 0; i < 2; ++i) {
    const int lin = i * 256 + tid;       // 0..511
    const int row = lin >> 3;            // 0..63
    const int colb = (lin & 7) * 16;
    const int scol = colb ^ ((row & 7) << 4);
    stK[i] = row * HD + (scol >> 1);
    stV[i] = row * S_LEN + (scol >> 1);
    stL[i] = lin * 8;
  }
  const int swz = (q31 & 7) << 4;

#define STAGE(t, buf)                                                          \
  {                                                                            \
    const bf16* kb_ = Kb + (size_t)(t) * 64 * HD;                              \
    const bf16* vb_ = Vb + (t) * 64;                                           \
    _Pragma("unroll") for (int i = 0; i < 2; ++i) {                            \
      gload_lds16(kb_ + stK[i], &Kl[buf][stL[i]]);                             \
      gload_lds16(vb_ + stV[i], &Vl[buf][stL[i]]);                             \
    }                                                                          \
  }

  auto run_chunk = [&](const int q0, const int nt) {
    const int q0w = q0 + (qh << 5);
    const int qg = q0w + q31;
    const int nt_w = (w == 1) ? nt - 1 : nt;   // w1's key-half never reaches diag
    const bool maskw = (w == 0) || (w == 3);   // triangular waves

    bf16x8 qf[4];
#pragma unroll
    for (int ks = 0; ks < 4; ++ks)
      qf[ks] = *(const bf16x8*)&Qb[(size_t)qg * HD + ks * 16 + 8 * h];

    f32x16 acc0 = {}, acc1 = {};
    float m = -1e30f, l = 0.f;

    // prologue: tiles 0,1 (tile index <=31 always in-bounds for the head)
    STAGE(0, 0)
    STAGE(1, 1)

    int cur = 0;
    for (int kt = 0; kt < nt; ++kt) {
      // tile kt landed when only tile kt+1's 4 stage-instrs are outstanding
      if (kt + 1 < nt) asm volatile("s_waitcnt vmcnt(4)" ::: "memory");
      else             asm volatile("s_waitcnt vmcnt(0)" ::: "memory");
      __builtin_amdgcn_s_barrier();

      if (kt + 2 < nt) {
        int nxt = cur + 2; if (nxt >= 3) nxt -= 3;
        STAGE(kt + 2, nxt)
      }

      if (kt < nt_w) {
        const bf16* KlC = &Kl[cur][0];
        const bf16* VlC = &Vl[cur][0];

        // K A-frags: 32 keys at koff (row = koff+q31; (koff+q31)&7 == q31&7)
        bf16x8 kf[4];
#pragma unroll
        for (int ks = 0; ks < 4; ++ks) {
          const int c = (32 * ks + 16 * h) ^ swz;
          kf[ks] = *(const bf16x8*)((const char*)KlC + (koff + q31) * 128 + c);
        }

        // ---- QK^T (32q x 32k x 64d = 4 mfma) ----
        f32x16 p0 = {};
        __builtin_amdgcn_s_setprio(1);
#pragma unroll
        for (int ks = 0; ks < 4; ++ks)
          p0 = __builtin_amdgcn_mfma_f32_32x32x16_bf16(kf[ks], qf[ks], p0, 0, 0, 0);
        __builtin_amdgcn_s_setprio(0);

        // V A-frags (rows d, cols = wave's 32-key half)
        bf16x8 vf[4];
#pragma unroll
        for (int ks = 0; ks < 2; ++ks)
#pragma unroll
          for (int db = 0; db < 2; ++db) {
            const int c = (64 * kh + 32 * ks + 16 * h) ^ swz;
            vf[ks * 2 + db] =
                *(const bf16x8*)((const char*)VlC + (db * 32 + q31) * 128 + c);
          }

        // ---- causal mask (diag tile, triangular waves only) ----
        if (maskw && kt == nt - 1) {
#pragma unroll
          for (int r = 0; r < 16; ++r) {
            const int key = (kt << 6) + koff + (r & 3) + 8 * (r >> 2) + 4 * h;
            if (key > qg) p0[r] = -1e30f;
          }
        }
        // ---- tree max over 16 + cross-half shuffle ----
        float t_[16];
#pragma unroll
        for (int r = 0; r < 16; ++r) t_[r] = p0[r];
#pragma unroll
        for (int s = 8; s >= 1; s >>= 1)
#pragma unroll
          for (int r = 0; r < s; ++r) t_[r] = fmaxf(t_[r], t_[r + s]);
        const float pmax = fmaxf(t_[0], __shfl_xor(t_[0], 32));
        // ---- defer-max (T13) ----
        if (!__all(pmax - m <= 8.0f)) {
          const float mn = fmaxf(m, pmax);
          const float al = exp2f(m - mn);
          m = mn;
          l *= al;
#pragma unroll
          for (int r = 0; r < 16; ++r) { acc0[r] *= al; acc1[r] *= al; }
        }
        // ---- exp + tree sum ----
        float sv[16];
#pragma unroll
        for (int r = 0; r < 16; ++r) {
          p0[r] = exp2f(p0[r] - m);
          sv[r] = p0[r];
        }
#pragma unroll
        for (int s = 8; s >= 1; s >>= 1)
#pragma unroll
          for (int r = 0; r < s; ++r) sv[r] += sv[r + s];
        l += sv[0] + __shfl_xor(sv[0], 32);

        // ---- pack P -> 2 PV B-frags via permlane32_swap ----
        unsigned wv[8];
#pragma unroll
        for (int mm = 0; mm < 8; ++mm)
          wv[mm] = packbf(p0[2 * mm], p0[2 * mm + 1]);
        pl32swap(wv[0], wv[2]);
        pl32swap(wv[1], wv[3]);
        pl32swap(wv[4], wv[6]);
        pl32swap(wv[5], wv[7]);

        // ---- PV (2 k-steps x 2 d-halves) ----
        __builtin_amdgcn_s_setprio(1);
        {
          u32x4 pu0 = {wv[0], wv[1], wv[2], wv[3]};
          const bf16x8 pf0 = __builtin_bit_cast(bf16x8, pu0);
          acc0 = __builtin_amdgcn_mfma_f32_32x32x16_bf16(vf[0], pf0, acc0, 0, 0, 0);
          acc1 = __builtin_amdgcn_mfma_f32_32x32x16_bf16(vf[1], pf0, acc1, 0, 0, 0);
          u32x4 pu1 = {wv[4], wv[5], wv[6], wv[7]};
          const bf16x8 pf1 = __builtin_bit_cast(bf16x8, pu1);
          acc0 = __builtin_amdgcn_mfma_f32_32x32x16_bf16(vf[2], pf1, acc0, 0, 0, 0);
          acc1 = __builtin_amdgcn_mfma_f32_32x32x16_bf16(vf[3], pf1, acc1, 0, 0, 0);
        }
        __builtin_amdgcn_s_setprio(0);
      }

      ++cur; if (cur == 3) cur = 0;
    }

    // ---- split-K combine across key-half waves (scratch = Kl area) ----
    float* scr = (float*)&Kl[0][0];
    float* s = scr + (size_t)qh * (64 * 34) + lane * 34;
    __syncthreads();  // all reads of ring done; safe to reuse as scratch
    if (kh) {
#pragma unroll
      for (int r = 0; r < 16; ++r) { s[r] = acc0[r]; s[16 + r] = acc1[r]; }
      s[32] = m;
      s[33] = l;
    }
    __syncthreads();
    if (!kh) {
      const float m1 = s[32], l1 = s[33];
      const float mn = fmaxf(m, m1);
      const float a0 = exp2f(m - mn), a1 = exp2f(m1 - mn);
      const float linv = 1.0f / (a0 * l + a1 * l1);
      const int b = bh >> 4, hh = bh & 15;
      bf16* orow = AO + ((size_t)(b * S_LEN + qg)) * DM + hh * HD;
#pragma unroll
      for (int mm = 0; mm < 4; ++mm) {
        bf16x4 ov0, ov1;
#pragma unroll
        for (int t2 = 0; t2 < 4; ++t2) {
          ov0[t2] = (bf16)((a0 * acc0[4 * mm + t2] + a1 * s[4 * mm + t2]) * linv);
          ov1[t2] = (bf16)((a0 * acc1[4 * mm + t2] + a1 * s[16 + 4 * mm + t2]) * linv);
        }
        *(bf16x4*)&orow[8 * mm + 4 * h] = ov0;
        *(bf16x4*)&orow[32 + 8 * mm + 4 * h] = ov1;
      }
    }
    __syncthreads();  // scratch reads done before next phase's staging
  };

  // phase A: light chunk p (p+1 tiles); phase B: heavy chunk 31-p (32-p tiles)
  run_chunk(p << 6, p + 1);
  run_chunk((31 - p) << 6, 32 - p);
#undef STAGE
}

// ---------------- launch ----------------
extern "C" void kernel_launch(void* const* d_in, const int* in_sizes, int n_in,
                              void* d_out, int out_size, void* d_ws, size_t ws_size,
                              hipStream_t stream) {
  const float* q  = (const float*)d_in[0];
  const float* k  = (const float*)d_in[1];
  const float* v  = (const float*)d_in[2];
  const float* Wq = (const float*)d_in[3];
  const float* bq = (const float*)d_in[4];
  const float* Wk = (const float*)d_in[5];
  const float* bk = (const float*)d_in[6];
  const float* Wv = (const float*)d_in[7];
  const float* bv = (const float*)d_in[8];
  const float* Wo = (const float*)d_in[9];
  const float* bo = (const float*)d_in[10];

  const int NTOK = 2 * S_LEN;          // 4096

  bf16* qb  = (bf16*)d_ws;             // q,k,v bf16: 3 * NQKV (consecutive)
  bf16* Wqb = qb + 3 * (size_t)NQKV;   // Wq,Wk,Wv,Wo bf16: 4 * NW (consecutive)
  bf16* Wob = Wqb + 3 * (size_t)NW;
  bf16* Qh  = Wqb + 4 * (size_t)NW;    // Qh,Kh,Vt bf16: 3 * NQKV (consecutive)
  bf16* Kh  = Qh + (size_t)NQKV;
  bf16* Vt  = Kh + (size_t)NQKV;
  bf16* AO  = Vt + (size_t)NQKV;

  const int cvt_blocks = (3 * NQKV + 4 * NW) / 8 / 256;
  cvt_all<<<cvt_blocks, 256, 0, stream>>>(q, k, v, Wq, Wk, Wv, Wo, qb);

  // fused QKV projection: M=4096, N=3072, K=1024
  gemm_bt<3><<<dim3(3 * DM / 128, NTOK / 128), 256, 0, stream>>>(
      qb, Wqb, bq, bk, bv, Qh, NTOK, 3 * DM, DM, QK_SCALE);

  // attention: 512 equal-work blocks x 256 threads
  attn_fwd8<<<dim3(512), 256, 0, stream>>>(Qh, Kh, Vt, AO);

  // output projection -> fp32 d_out
  gemm_bt<2><<<dim3(DM / 128, NTOK / 128), 256, 0, stream>>>(
      AO, Wob, bo, bo, bo, d_out, NTOK, DM, DM, 1.0f);
}